// Round 1
// baseline (177.452 us; speedup 1.0000x reference)
//
#include <hip/hip_runtime.h>
#include <math.h>

#define BLK 256

// Build node tile into LDS, layout nd[(u*X + x)*Dd*R + d*R + r].
// node(u,x,d,r) = x0*T0[g] + x1*T1[g], g = u*su + x*sx + d*sd + r*sr
// site points at peps[i][j][p=0]; p=1 slice at +1296.
__device__ __forceinline__ void build_tile(
    float* __restrict__ nd, const float* __restrict__ site,
    float x0, float x1,
    int U, int X, int Dd, int R,
    int su, int sx, int sd, int sr, int tid)
{
    const int DR = Dd * R;
    const int total = U * X * DR;
    for (int idx = tid; idx < total; idx += BLK) {
        int u   = idx / (X * DR);
        int rem = idx - u * (X * DR);
        int x   = rem / DR;
        int dr  = rem - x * DR;
        int d   = dr / R;
        int r   = dr - d * R;
        int g = u * su + x * sx + d * sd + r * sr;
        nd[idx] = x0 * site[g] + x1 * site[g + 1296];
    }
}

// out[m*36 + dr] = sum_{u,x} S[(u*M+m)*X + x] * nd[(u*X+x)*36 + dr], DR==36
// 4-wide: each thread computes 4 consecutive dr via float4 LDS loads.
__device__ __forceinline__ void contract_vec36(
    const float* __restrict__ S, const float* __restrict__ nd,
    float* __restrict__ out, int M, int U, int X, int tid)
{
    const int total = M * 9;
    for (int t = tid; t < total; t += BLK) {
        int m = t / 9;
        int dr0 = (t - m * 9) * 4;
        float4 acc = make_float4(0.f, 0.f, 0.f, 0.f);
        for (int u = 0; u < U; ++u) {
            const float* Srow = S + (u * M + m) * X;
            const float* Nrow = nd + u * X * 36 + dr0;
            for (int x = 0; x < X; ++x) {
                float s = Srow[x];
                float4 n4 = *reinterpret_cast<const float4*>(Nrow + x * 36);
                acc.x = fmaf(s, n4.x, acc.x);
                acc.y = fmaf(s, n4.y, acc.y);
                acc.z = fmaf(s, n4.z, acc.z);
                acc.w = fmaf(s, n4.w, acc.w);
            }
        }
        *reinterpret_cast<float4*>(out + m * 36 + dr0) = acc;
    }
}

// generic scalar path (for DR==6 tail steps)
__device__ __forceinline__ void contract_scalar(
    const float* __restrict__ S, const float* __restrict__ nd,
    float* __restrict__ out, int M, int U, int X, int DR, int tid)
{
    const int total = M * DR;
    for (int idx = tid; idx < total; idx += BLK) {
        int m  = idx / DR;
        int dr = idx - m * DR;
        float acc = 0.f;
        for (int u = 0; u < U; ++u) {
            const float* Srow = S + (u * M + m) * X;
            const float* Nrow = nd + u * X * DR + dr;
            for (int x = 0; x < X; ++x)
                acc = fmaf(Srow[x], Nrow[x * DR], acc);
        }
        out[idx] = acc;
    }
}

__global__ __launch_bounds__(BLK)
void peps_fwd(const float* __restrict__ inputs,
              const float* __restrict__ peps,
              const float* __restrict__ pepsc,
              float* __restrict__ out)
{
    // ~78 KB LDS -> 2 blocks/CU on gfx950 (160 KiB/CU)
    __shared__ __align__(16) float A[7776];
    __shared__ __align__(16) float Bf[7776];
    __shared__ __align__(16) float EB[1296];   // env_bot
    __shared__ __align__(16) float ND[1296];   // node tile
    __shared__ __align__(16) float T1b[1296];
    __shared__ float xs[32];
    __shared__ float red[52];

    const int b   = blockIdx.x;
    const int tid = threadIdx.x;

    // x values scaled by 100: constant per-node rescale, absorbed by final
    // normalization; keeps the unnormalized contraction chain in fp32 range.
    if (tid < 32) xs[tid] = inputs[b * 32 + tid] * 100.0f;
    __syncthreads();

    // ================= bottom row (i=3) -> EB[d0,d1,d2,d3] =================
    {   // S0[u0*6+r0] = node(3,0)[u0, r0, d=0, l=0]
        const float* s = peps + (size_t)(3 * 4 + 0) * 2 * 1296;
        float x0 = xs[24], x1 = xs[25];
        for (int idx = tid; idx < 36; idx += BLK) {
            int u = idx / 6, r = idx - u * 6;
            int g = u * 216 + r * 36;
            A[idx] = x0 * s[g] + x1 * s[g + 1296];
        }
    }
    __syncthreads();
    // j=1: out[M=1? m=u0][u1][r1]; roles: D->u leg (s=216), R->r (s=36), x=l
    build_tile(ND, peps + (size_t)13 * 2 * 1296, xs[26], xs[27], 1, 6, 6, 6, 0, 1, 216, 36, tid);
    __syncthreads();
    contract_vec36(A, ND, Bf, 6, 1, 6, tid);          // Bf: 216
    __syncthreads();
    build_tile(ND, peps + (size_t)14 * 2 * 1296, xs[28], xs[29], 1, 6, 6, 6, 0, 1, 216, 36, tid);
    __syncthreads();
    contract_vec36(Bf, ND, A, 36, 1, 6, tid);         // A: 1296
    __syncthreads();
    // j=3: node(3,3)[u, r=0, d=0, l]: D->u (216), R=1
    build_tile(ND, peps + (size_t)15 * 2 * 1296, xs[30], xs[31], 1, 6, 6, 1, 0, 1, 216, 0, tid);
    __syncthreads();
    contract_scalar(A, ND, EB, 216, 1, 6, 6, tid);    // EB: 1296
    __syncthreads();

    // ================= top row (i=0) -> E0 in Bf =================
    {   // S0[d0*6+r0] = node(0,0)[u=0, r0, d0, l=0]
        const float* s = peps;
        float x0 = xs[0], x1 = xs[1];
        for (int idx = tid; idx < 36; idx += BLK) {
            int d = idx / 6, r = idx - d * 6;
            int g = r * 36 + d * 6;
            A[idx] = x0 * s[g] + x1 * s[g + 1296];
        }
    }
    __syncthreads();
    // roles: D->d (s=6), R->r (s=36), x=l
    build_tile(ND, peps + (size_t)1 * 2 * 1296, xs[2], xs[3], 1, 6, 6, 6, 0, 1, 6, 36, tid);
    __syncthreads();
    contract_vec36(A, ND, Bf, 6, 1, 6, tid);          // Bf: 216
    __syncthreads();
    build_tile(ND, peps + (size_t)2 * 2 * 1296, xs[4], xs[5], 1, 6, 6, 6, 0, 1, 6, 36, tid);
    __syncthreads();
    contract_vec36(Bf, ND, A, 36, 1, 6, tid);         // A: 1296
    __syncthreads();
    // j=3: r sliced -> R=1
    build_tile(ND, peps + (size_t)3 * 2 * 1296, xs[6], xs[7], 1, 6, 6, 1, 0, 1, 6, 0, tid);
    __syncthreads();
    contract_scalar(A, ND, Bf, 216, 1, 6, 6, tid);    // Bf = E0: 1296
    __syncthreads();

    // ================= row 1 -> env_top in Bf =================
    // j=0: l sliced -> X=1; U=u (216), D=d (6), R=r (36)
    build_tile(ND, peps + (size_t)4 * 2 * 1296, xs[8], xs[9], 6, 1, 6, 6, 216, 0, 6, 36, tid);
    __syncthreads();
    contract_vec36(Bf, ND, A, 216, 6, 1, tid);        // A: 7776
    __syncthreads();
    build_tile(ND, peps + (size_t)5 * 2 * 1296, xs[10], xs[11], 6, 6, 6, 6, 216, 1, 6, 36, tid);
    __syncthreads();
    contract_vec36(A, ND, Bf, 216, 6, 6, tid);        // Bf: 7776
    __syncthreads();
    build_tile(ND, peps + (size_t)6 * 2 * 1296, xs[12], xs[13], 6, 6, 6, 6, 216, 1, 6, 36, tid);
    __syncthreads();
    contract_vec36(Bf, ND, A, 216, 6, 6, tid);        // A: 7776
    __syncthreads();
    // j=3: r sliced -> R=1
    build_tile(ND, peps + (size_t)7 * 2 * 1296, xs[14], xs[15], 6, 6, 6, 1, 216, 1, 6, 0, tid);
    __syncthreads();
    contract_scalar(A, ND, Bf, 216, 6, 6, 6, tid);    // Bf = env_top: 1296
    __syncthreads();

    // ================= center row pre (i=2, j=0,1) -> S_pre in Bf =================
    build_tile(ND, peps + (size_t)8 * 2 * 1296, xs[16], xs[17], 6, 1, 6, 6, 216, 0, 6, 36, tid);
    __syncthreads();
    contract_vec36(Bf, ND, A, 216, 6, 1, tid);        // A: 7776
    __syncthreads();
    build_tile(ND, peps + (size_t)9 * 2 * 1296, xs[18], xs[19], 6, 6, 6, 6, 216, 1, 6, 36, tid);
    __syncthreads();
    contract_vec36(A, ND, Bf, 216, 6, 6, tid);        // Bf = S_pre[u2,u3,d0,d1,r1]
    __syncthreads();

    // ================= NT(2,3) and K = env_bot x N23 =================
    {   // NT[(u3*6+d3)*6+r2] = node(2,3)[u3, r=0, d3, l=r2]
        const float* s = peps + (size_t)11 * 2 * 1296;
        float x0 = xs[22], x1 = xs[23];
        for (int idx = tid; idx < 216; idx += BLK) {
            int u3 = idx / 36;
            int d3 = (idx / 6) % 6;
            int r2 = idx % 6;
            int g = u3 * 216 + d3 * 6 + r2;
            ND[idx] = x0 * s[g] + x1 * s[g + 1296];
        }
    }
    __syncthreads();
    // K[u3*1296 + g*6 + r2] = sum_d3 EB[g*6+d3] * NT[(u3*6+d3)*6+r2], g=(d0,d1,d2)
    for (int k = tid; k < 7776; k += BLK) {
        int u3  = k / 1296;
        int rem = k - u3 * 1296;
        int g   = rem / 6;
        int r2  = rem - g * 6;
        float acc = 0.f;
        #pragma unroll
        for (int d3 = 0; d3 < 6; ++d3)
            acc = fmaf(EB[g * 6 + d3], ND[(u3 * 6 + d3) * 6 + r2], acc);
        A[k] = acc;                                    // A = K: 7776
    }
    __syncthreads();

    // ================= T1[u2,r1,d2,r2] = sum_{h=(u3,d0,d1)} S_pre * K =========
    for (int t = tid; t < 324; t += BLK) {
        int o4  = t * 4;
        int u2  = o4 / 216;
        int r1  = (o4 / 36) % 6;
        int dr0 = o4 % 36;                             // (d2*6+r2) tile of 4
        float4 acc = make_float4(0.f, 0.f, 0.f, 0.f);
        const float* Sb = Bf + u2 * 1296 + r1;
        for (int h = 0; h < 216; ++h) {
            float s = Sb[h * 6];
            float4 k4 = *reinterpret_cast<const float4*>(A + h * 36 + dr0);
            acc.x = fmaf(s, k4.x, acc.x);
            acc.y = fmaf(s, k4.y, acc.y);
            acc.z = fmaf(s, k4.z, acc.z);
            acc.w = fmaf(s, k4.w, acc.w);
        }
        *reinterpret_cast<float4*>(T1b + o4) = acc;
    }
    __syncthreads();

    // ================= out[o] = sum T1[u2,r1,d2,r2] * C_o[u2,r2,d2,r1] =======
    float part[10];
    #pragma unroll
    for (int o = 0; o < 10; ++o) part[o] = 0.f;
    {
        float x0 = xs[20], x1 = xs[21];
        for (int e = tid; e < 1296; e += BLK) {
            float t1 = T1b[e];
            int u2 = e / 216;
            int r1 = (e / 36) % 6;
            int d2 = (e / 6) % 6;
            int r2 = e % 6;
            int coff = u2 * 216 + r2 * 36 + d2 * 6 + r1;
            #pragma unroll
            for (int o = 0; o < 10; ++o) {
                float c = x0 * pepsc[o * 1296 + coff]
                        + x1 * pepsc[(10 + o) * 1296 + coff];
                part[o] = fmaf(t1, c, part[o]);
            }
        }
    }
    // wave(64) shuffle reduce, then cross-wave via LDS
    #pragma unroll
    for (int off = 32; off >= 1; off >>= 1) {
        #pragma unroll
        for (int o = 0; o < 10; ++o)
            part[o] += __shfl_down(part[o], off, 64);
    }
    int lane = tid & 63, wid = tid >> 6;
    if (lane == 0) {
        #pragma unroll
        for (int o = 0; o < 10; ++o) red[wid * 10 + o] = part[o];
    }
    __syncthreads();
    if (tid < 10) {
        red[40 + tid] = red[tid] + red[10 + tid] + red[20 + tid] + red[30 + tid];
    }
    __syncthreads();
    if (tid == 0) {
        float n2 = 0.f;
        #pragma unroll
        for (int o = 0; o < 10; ++o) n2 += red[40 + o] * red[40 + o];
        red[50] = 1.0f / sqrtf(n2);
    }
    __syncthreads();
    if (tid < 10) out[b * 10 + tid] = red[40 + tid] * red[50];
}

extern "C" void kernel_launch(void* const* d_in, const int* in_sizes, int n_in,
                              void* d_out, int out_size, void* d_ws, size_t ws_size,
                              hipStream_t stream) {
    const float* inputs = (const float*)d_in[0];   // (B,4,4,2) f32
    const float* peps   = (const float*)d_in[1];   // (4,4,2,6,6,6,6) f32
    const float* pepsc  = (const float*)d_in[2];   // (2,10,6,6,6,6) f32
    float* out = (float*)d_out;                    // (B,10) f32
    const int B = in_sizes[0] / 32;
    peps_fwd<<<dim3(B), dim3(BLK), 0, stream>>>(inputs, peps, pepsc, out);
}

// Round 2
// 136.142 us; speedup vs baseline: 1.3034x; 1.3034x over previous
//
#include <hip/hip_runtime.h>
#include <math.h>

#define BLK 256

// Build node tile into LDS, layout nd[(u*X + x)*Dd*R + d*R + r].
// node(u,x,d,r) = x0*T0[g] + x1*T1[g], g = u*su + x*sx + d*sd + r*sr
__device__ __forceinline__ void build_tile(
    float* __restrict__ nd, const float* __restrict__ site,
    float x0, float x1,
    int U, int X, int Dd, int R,
    int su, int sx, int sd, int sr, int tid)
{
    const int DR = Dd * R;
    const int total = U * X * DR;
    for (int idx = tid; idx < total; idx += BLK) {
        int u   = idx / (X * DR);
        int rem = idx - u * (X * DR);
        int x   = rem / DR;
        int dr  = rem - x * DR;
        int d   = dr / R;
        int r   = dr - d * R;
        int g = u * su + x * sx + d * sd + r * sr;
        nd[idx] = x0 * site[g] + x1 * site[g + 1296];
    }
}

// out[m*36 + dr] = sum_{u<U,x<X} S[(u*M+m)*X + x] * N[(u*X+x)*36 + dr]
// Register-blocked: MT m-values x 4 dr per thread; N float4 reused across MT.
template<int MT, int U, int X>
__device__ __forceinline__ void contract36(
    const float* __restrict__ S, const float* __restrict__ N,
    float* __restrict__ out, int M, int tid)
{
    const int total = (M / MT) * 9;
    for (int t = tid; t < total; t += BLK) {
        int mi = t / 9;
        int di = t - mi * 9;
        int m0 = mi * MT, dr0 = di * 4;
        float4 acc[MT];
        #pragma unroll
        for (int i = 0; i < MT; ++i) acc[i] = make_float4(0.f, 0.f, 0.f, 0.f);
        #pragma unroll
        for (int u = 0; u < U; ++u) {
            const float* Sb = S + (u * M + m0) * X;
            const float* Nb = N + u * X * 36 + dr0;
            #pragma unroll
            for (int x = 0; x < X; ++x) {
                float4 n4 = *reinterpret_cast<const float4*>(Nb + x * 36);
                #pragma unroll
                for (int i = 0; i < MT; ++i) {
                    float s = Sb[i * X + x];
                    acc[i].x = fmaf(s, n4.x, acc[i].x);
                    acc[i].y = fmaf(s, n4.y, acc[i].y);
                    acc[i].z = fmaf(s, n4.z, acc[i].z);
                    acc[i].w = fmaf(s, n4.w, acc[i].w);
                }
            }
        }
        #pragma unroll
        for (int i = 0; i < MT; ++i)
            *reinterpret_cast<float4*>(out + (m0 + i) * 36 + dr0) = acc[i];
    }
}

// out[m*6 + d] = sum_{u,x} S[(u*M+m)*X + x] * N[(u*X+x)*6 + d]
template<int U, int X>
__device__ __forceinline__ void contract_tail6(
    const float* __restrict__ S, const float* __restrict__ N,
    float* __restrict__ out, int M, int tid)
{
    for (int m = tid; m < M; m += BLK) {
        float acc[6];
        #pragma unroll
        for (int d = 0; d < 6; ++d) acc[d] = 0.f;
        #pragma unroll
        for (int u = 0; u < U; ++u) {
            const float* Sb = S + (u * M + m) * X;
            const float* Nb = N + u * X * 6;
            #pragma unroll
            for (int x = 0; x < X; ++x) {
                float s = Sb[x];
                const float* Nr = Nb + x * 6;
                float2 n01 = *reinterpret_cast<const float2*>(Nr);
                float2 n23 = *reinterpret_cast<const float2*>(Nr + 2);
                float2 n45 = *reinterpret_cast<const float2*>(Nr + 4);
                acc[0] = fmaf(s, n01.x, acc[0]);
                acc[1] = fmaf(s, n01.y, acc[1]);
                acc[2] = fmaf(s, n23.x, acc[2]);
                acc[3] = fmaf(s, n23.y, acc[3]);
                acc[4] = fmaf(s, n45.x, acc[4]);
                acc[5] = fmaf(s, n45.y, acc[5]);
            }
        }
        #pragma unroll
        for (int d = 0; d < 6; ++d) out[m * 6 + d] = acc[d];
    }
}

__global__ __launch_bounds__(BLK)
void peps_fwd(const float* __restrict__ inputs,
              const float* __restrict__ peps,
              const float* __restrict__ pepsc,
              float* __restrict__ out)
{
    // 80.1 KB LDS -> 2 blocks/CU (160 KiB/CU)
    __shared__ __align__(16) float A[7776];
    __shared__ __align__(16) float Bf[7776];
    __shared__ __align__(16) float EB[1296];   // env_bot; later T1
    __shared__ __align__(16) float AR[3104];   // tile arena / T1 partials
    __shared__ float xs[32];
    __shared__ float red[52];

    const int b   = blockIdx.x;
    const int tid = threadIdx.x;

    #define SITE(i, j) (peps + (size_t)((i) * 4 + (j)) * 2 * 1296)

    // x scaled by 100: constant per-node rescale, absorbed by final norm;
    // keeps the unnormalized chain in fp32 range.
    if (tid < 32) xs[tid] = inputs[b * 32 + tid] * 100.0f;
    __syncthreads();

    // ---- P1: tiles for row3 + row0, and both chain inits ----
    build_tile(AR + 0,   SITE(3,1), xs[26], xs[27], 1,6,6,6, 0,1,216,36, tid);
    build_tile(AR + 216, SITE(3,2), xs[28], xs[29], 1,6,6,6, 0,1,216,36, tid);
    build_tile(AR + 432, SITE(3,3), xs[30], xs[31], 1,6,6,1, 0,1,216,0,  tid);
    build_tile(AR + 468, SITE(0,1), xs[2],  xs[3],  1,6,6,6, 0,1,6,36,   tid);
    build_tile(AR + 684, SITE(0,2), xs[4],  xs[5],  1,6,6,6, 0,1,6,36,   tid);
    build_tile(AR + 900, SITE(0,3), xs[6],  xs[7],  1,6,6,1, 0,1,6,0,    tid);
    {
        const float* s3 = SITE(3,0);
        const float* s0 = SITE(0,0);
        for (int idx = tid; idx < 36; idx += BLK) {
            int u = idx / 6, r = idx - (idx / 6) * 6;
            // S_r3[u0*6+r0] = node(3,0)[u,r]  (d=0,l=0)
            A[idx]        = xs[24] * s3[u*216 + r*36] + xs[25] * s3[u*216 + r*36 + 1296];
            // S_r0[d0*6+r0] = node(0,0)[r,d]  (u=0,l=0), d plays 'u' here
            A[2048 + idx] = xs[0]  * s0[r*36 + u*6]   + xs[1]  * s0[r*36 + u*6 + 1296];
        }
    }
    __syncthreads();

    // ---- P2: row3 j=1 & row0 j=1 (independent chains, disjoint regions) ----
    contract36<1,1,6>(A,        AR + 0,   Bf,        6, tid);
    contract36<1,1,6>(A + 2048, AR + 468, Bf + 2048, 6, tid);
    __syncthreads();

    // ---- P3: row3 j=2 & row0 j=2 ----
    contract36<2,1,6>(Bf,        AR + 216, A,        36, tid);
    contract36<2,1,6>(Bf + 2048, AR + 684, A + 2048, 36, tid);
    __syncthreads();

    // ---- P4: row3 j=3 -> EB ; row0 j=3 -> E0 in Bf[0:1296] ----
    contract_tail6<1,6>(A,        AR + 432, EB, 216, tid);
    contract_tail6<1,6>(A + 2048, AR + 900, Bf, 216, tid);
    __syncthreads();

    // ---- P5: row1 tiles ----
    build_tile(AR + 0,    SITE(1,0), xs[8],  xs[9],  6,1,6,6, 216,0,6,36, tid);
    build_tile(AR + 216,  SITE(1,1), xs[10], xs[11], 6,6,6,6, 216,1,6,36, tid);
    build_tile(AR + 1512, SITE(1,2), xs[12], xs[13], 6,6,6,6, 216,1,6,36, tid);
    build_tile(AR + 2808, SITE(1,3), xs[14], xs[15], 6,6,6,1, 216,1,6,0,  tid);
    __syncthreads();

    // ---- P6..P9: row1 ----
    contract36<8,6,1>(Bf, AR + 0, A, 216, tid);          // j=0: 1296 -> 7776
    __syncthreads();
    contract36<8,6,6>(A, AR + 216, Bf, 216, tid);        // j=1 (big)
    __syncthreads();
    contract36<8,6,6>(Bf, AR + 1512, A, 216, tid);       // j=2 (big)
    __syncthreads();
    // j=3 -> env_top in Bf[0:1296]; also build row2 tiles (disjoint regions)
    contract_tail6<6,6>(A, AR + 2808, Bf, 216, tid);
    build_tile(AR + 0,   SITE(2,0), xs[16], xs[17], 6,1,6,6, 216,0,6,36, tid);
    build_tile(AR + 216, SITE(2,1), xs[18], xs[19], 6,6,6,6, 216,1,6,36, tid);
    {   // NT(2,3): nd[(u3*6+d3)*6+r2] = T[u3, r=0, d3, l=r2]
        const float* s = SITE(2,3);
        for (int idx = tid; idx < 216; idx += BLK) {
            int u3 = idx / 36;
            int d3 = (idx / 6) % 6;
            int r2 = idx % 6;
            int g = u3 * 216 + d3 * 6 + r2;
            AR[1512 + idx] = xs[22] * s[g] + xs[23] * s[g + 1296];
        }
    }
    __syncthreads();

    // ---- P10/P11: row2 pre ----
    contract36<8,6,1>(Bf, AR + 0, A, 216, tid);          // j=0
    __syncthreads();
    contract36<8,6,6>(A, AR + 216, Bf, 216, tid);        // j=1 -> S_pre in Bf
    __syncthreads();

    // ---- P12: K[h*36 + d2*6 + r2] = sum_d3 EB[g*6+d3]*NT[(u3*6+d3)*6+r2] -> A
    for (int k = tid; k < 7776; k += BLK) {
        int u3  = k / 1296;
        int rem = k - u3 * 1296;
        int g   = rem / 6;
        int r2  = rem - g * 6;
        float acc = 0.f;
        #pragma unroll
        for (int d3 = 0; d3 < 6; ++d3)
            acc = fmaf(EB[g * 6 + d3], AR[1512 + (u3 * 6 + d3) * 6 + r2], acc);
        A[k] = acc;
    }
    __syncthreads();

    // ---- P13: T1[(u2*6+r1)*36 + d2*6+r2] = sum_h S_pre[u2,h,r1]*K[h,dr]
    // split-k=2 partials into AR[0:2592] (tiles dead)
    for (int t = tid; t < 162; t += BLK) {
        int c   = t / 81;
        int rem = t - c * 81;
        int mi  = rem / 9;
        int di  = rem - mi * 9;
        int m0 = mi * 4, dr0 = di * 4;
        float4 acc[4];
        const float* Sp[4];
        #pragma unroll
        for (int i = 0; i < 4; ++i) {
            acc[i] = make_float4(0.f, 0.f, 0.f, 0.f);
            int mm = m0 + i;
            int u2 = mm / 6, r1 = mm - u2 * 6;
            Sp[i] = Bf + u2 * 1296 + r1;
        }
        int h0 = c * 108, h1 = h0 + 108;
        for (int h = h0; h < h1; ++h) {
            float4 k4 = *reinterpret_cast<const float4*>(A + h * 36 + dr0);
            #pragma unroll
            for (int i = 0; i < 4; ++i) {
                float s = Sp[i][h * 6];
                acc[i].x = fmaf(s, k4.x, acc[i].x);
                acc[i].y = fmaf(s, k4.y, acc[i].y);
                acc[i].z = fmaf(s, k4.z, acc[i].z);
                acc[i].w = fmaf(s, k4.w, acc[i].w);
            }
        }
        #pragma unroll
        for (int i = 0; i < 4; ++i)
            *reinterpret_cast<float4*>(AR + c * 1296 + (m0 + i) * 36 + dr0) = acc[i];
    }
    __syncthreads();

    // ---- P14: reduce split-k -> T1 in EB (env_bot dead after P12) ----
    for (int e = tid; e < 1296; e += BLK)
        EB[e] = AR[e] + AR[1296 + e];
    __syncthreads();

    // ---- P15: out[o] = sum_e T1[e] * (x20*C0 + x21*C1)[coff], normalize ----
    float part[10];
    #pragma unroll
    for (int o = 0; o < 10; ++o) part[o] = 0.f;
    {
        float x0 = xs[20], x1 = xs[21];
        for (int e = tid; e < 1296; e += BLK) {
            float t1 = EB[e];
            int u2 = e / 216;
            int r1 = (e / 36) % 6;
            int d2 = (e / 6) % 6;
            int r2 = e % 6;
            int coff = u2 * 216 + r2 * 36 + d2 * 6 + r1;
            #pragma unroll
            for (int o = 0; o < 10; ++o) {
                float c = x0 * pepsc[o * 1296 + coff]
                        + x1 * pepsc[(10 + o) * 1296 + coff];
                part[o] = fmaf(t1, c, part[o]);
            }
        }
    }
    #pragma unroll
    for (int off = 32; off >= 1; off >>= 1) {
        #pragma unroll
        for (int o = 0; o < 10; ++o)
            part[o] += __shfl_down(part[o], off, 64);
    }
    int lane = tid & 63, wid = tid >> 6;
    if (lane == 0) {
        #pragma unroll
        for (int o = 0; o < 10; ++o) red[wid * 10 + o] = part[o];
    }
    __syncthreads();
    if (tid < 10)
        red[40 + tid] = red[tid] + red[10 + tid] + red[20 + tid] + red[30 + tid];
    __syncthreads();
    if (tid == 0) {
        float n2 = 0.f;
        #pragma unroll
        for (int o = 0; o < 10; ++o) n2 += red[40 + o] * red[40 + o];
        red[50] = 1.0f / sqrtf(n2);
    }
    __syncthreads();
    if (tid < 10) out[b * 10 + tid] = red[40 + tid] * red[50];
    #undef SITE
}

extern "C" void kernel_launch(void* const* d_in, const int* in_sizes, int n_in,
                              void* d_out, int out_size, void* d_ws, size_t ws_size,
                              hipStream_t stream) {
    const float* inputs = (const float*)d_in[0];   // (B,4,4,2) f32
    const float* peps   = (const float*)d_in[1];   // (4,4,2,6,6,6,6) f32
    const float* pepsc  = (const float*)d_in[2];   // (2,10,6,6,6,6) f32
    float* out = (float*)d_out;                    // (B,10) f32
    const int B = in_sizes[0] / 32;
    peps_fwd<<<dim3(B), dim3(BLK), 0, stream>>>(inputs, peps, pepsc, out);
}

// Round 3
// 129.898 us; speedup vs baseline: 1.3661x; 1.0481x over previous
//
#include <hip/hip_runtime.h>
#include <math.h>

#define BLK 256

__device__ __forceinline__ void fma4(float4& a, float s, const float4& n) {
    a.x = fmaf(s, n.x, a.x); a.y = fmaf(s, n.y, a.y);
    a.z = fmaf(s, n.z, a.z); a.w = fmaf(s, n.w, a.w);
}

__global__ __launch_bounds__(BLK, 4)
void peps_fwd(const float* __restrict__ inputs,
              const float* __restrict__ peps,
              const float* __restrict__ pepsc,
              float* __restrict__ out)
{
    // 40368 B LDS -> 4 blocks/CU (160 KiB), all 1024 blocks co-resident.
    __shared__ __align__(16) float E[7776];    // env, [m<216][k<36] row-major
    __shared__ __align__(16) float TA[720];    // big-tile half slot (<=20 k-rows x 36)
    __shared__ __align__(16) float TBs[216];   // small tiles
    __shared__ __align__(16) float EB[1296];   // env_bot [ (d0d1) ][ (d2d3) ]; later T1
    __shared__ float xs[32];
    __shared__ float red[52];

    const int b   = blockIdx.x;
    const int tid = threadIdx.x;

    #define SITE(i, j) (peps + (size_t)((i) * 4 + (j)) * 2 * 1296)

    // task decomposition for big GEMM steps (M=216, N=36): 243 tasks.
    // m = mi + 27*i (interleaved -> lanes read consecutive E rows: conflict-free)
    const int di  = tid % 9;
    const int mi  = tid / 9;
    const int dr0 = di * 4;
    const bool active = (tid < 243);

    float4 acc[8];

    // x scaled by 100: constant positive per-node rescale, absorbed by the
    // final normalization; keeps the unnormalized chain well inside fp32 range.
    if (tid < 32) xs[tid] = inputs[b * 32 + tid] * 100.0f;

    // ---- helpers ---------------------------------------------------------
    // boundary tile build: nd[x*Dd*R + d*R + r] = sum_p x_p * T[g]
    auto btile = [&](float* nd, const float* site, float x0, float x1,
                     int Dd, int R, int sx, int sd, int sr) {
        int tot = 6 * Dd * R;
        for (int idx = tid; idx < tot; idx += BLK) {
            int x = idx / (Dd * R), rem = idx % (Dd * R);
            int d = rem / R, r = rem % R;
            int g = x * sx + d * sd + r * sr;
            nd[idx] = x0 * site[g] + x1 * site[g + 1296];
        }
    };
    // big tile half: rows k in [k0,k0+kn), layout [k-k0][d*6+r], k=(u*6+l)
    auto build_big_half = [&](const float* site, float x0, float x1, int k0, int kn) {
        for (int idx = tid; idx < kn * 36; idx += BLK) {
            int k = k0 + idx / 36, n = idx % 36;
            int g = (k / 6) * 216 + (k % 6) + (n / 6) * 6 + (n % 6) * 36;
            TA[idx] = x0 * site[g] + x1 * site[g + 1296];
        }
    };
    auto acc_zero = [&]() {
        #pragma unroll
        for (int i = 0; i < 8; ++i) acc[i] = make_float4(0.f, 0.f, 0.f, 0.f);
    };
    // acc += E[:, k0+4*kb ...] * TH  (TH rows local from 0), kb_n blocks of 4 k
    auto big_compute = [&](const float* TH, int k0, int kb_n) {
        if (!active) return;
        for (int kb = 0; kb < kb_n; ++kb) {
            float4 s[8];
            #pragma unroll
            for (int i = 0; i < 8; ++i)
                s[i] = *(const float4*)&E[(mi + 27 * i) * 36 + k0 + kb * 4];
            const float* THb = TH + (kb * 4) * 36 + dr0;
            float4 n0 = *(const float4*)(THb);
            float4 n1 = *(const float4*)(THb + 36);
            float4 n2 = *(const float4*)(THb + 72);
            float4 n3 = *(const float4*)(THb + 108);
            #pragma unroll
            for (int i = 0; i < 8; ++i) {
                fma4(acc[i], s[i].x, n0);
                fma4(acc[i], s[i].y, n1);
                fma4(acc[i], s[i].z, n2);
                fma4(acc[i], s[i].w, n3);
            }
        }
    };
    // K=6 step: S = E cols 0..5, tile TH[k*36+n] (6 rows)
    auto big_K6 = [&](const float* TH) {
        if (!active) return;
        float4 s4[8]; float2 s2[8];
        #pragma unroll
        for (int i = 0; i < 8; ++i) {
            const float* Ei = &E[(mi + 27 * i) * 36];
            s4[i] = *(const float4*)(Ei);
            s2[i] = *(const float2*)(Ei + 4);
        }
        const float* THb = TH + dr0;
        float4 n0 = *(const float4*)(THb);
        float4 n1 = *(const float4*)(THb + 36);
        float4 n2 = *(const float4*)(THb + 72);
        float4 n3 = *(const float4*)(THb + 108);
        float4 n4 = *(const float4*)(THb + 144);
        float4 n5 = *(const float4*)(THb + 180);
        #pragma unroll
        for (int i = 0; i < 8; ++i) {
            fma4(acc[i], s4[i].x, n0);
            fma4(acc[i], s4[i].y, n1);
            fma4(acc[i], s4[i].z, n2);
            fma4(acc[i], s4[i].w, n3);
            fma4(acc[i], s2[i].x, n4);
            fma4(acc[i], s2[i].y, n5);
        }
    };
    // standard rotation store: out[m][(d,r)] -> rows (m%36)*6+d, col (m/36)*6+r
    auto write_rot = [&]() {
        if (!active) return;
        #pragma unroll
        for (int i = 0; i < 8; ++i) {
            int m = mi + 27 * i, mr = m % 36, mq = m / 36;
            float v0 = acc[i].x, v1 = acc[i].y, v2 = acc[i].z, v3 = acc[i].w;
            int dr;
            dr = dr0 + 0; E[(mr * 6 + dr / 6) * 36 + mq * 6 + dr % 6] = v0;
            dr = dr0 + 1; E[(mr * 6 + dr / 6) * 36 + mq * 6 + dr % 6] = v1;
            dr = dr0 + 2; E[(mr * 6 + dr / 6) * 36 + mq * 6 + dr % 6] = v2;
            dr = dr0 + 3; E[(mr * 6 + dr / 6) * 36 + mq * 6 + dr % 6] = v3;
        }
    };
    // boundary chain step, N=36, K=6: band cin -> band cout (band-rotation)
    auto chain36 = [&](int cin, int cout, const float* TL, int M) {
        for (int t2 = tid; t2 < M * 36; t2 += BLK) {
            int m = t2 / 36, n = t2 % 36;
            float a = 0.f;
            #pragma unroll
            for (int k = 0; k < 6; ++k)
                a = fmaf(E[m * 36 + cin + k], TL[k * 36 + n], a);
            E[(m * 6 + n / 6) * 36 + cout + n % 6] = a;
        }
    };

    __syncthreads();  // P0: xs ready

    // ---- P1: boundary tiles + chain inits --------------------------------
    btile(TA +   0, SITE(3,1), xs[26], xs[27], 6, 6, 1, 216, 36); // T31 [x][u*6+r]
    btile(TA + 216, SITE(0,1), xs[2],  xs[3],  6, 6, 1, 6,   36); // T01 [x][d*6+r]
    btile(TA + 432, SITE(3,3), xs[30], xs[31], 6, 1, 1, 216, 0);  // T33 [x][u]
    btile(TA + 468, SITE(0,3), xs[6],  xs[7],  6, 1, 1, 6,   0);  // T03 [x][d]
    {
        const float* s3 = SITE(3,0);
        const float* s0 = SITE(0,0);
        for (int idx = tid; idx < 36; idx += BLK) {
            int u = idx / 6, r = idx % 6;
            // row0 S0[d0][r0] -> band 6 ; row3 S0[u0][r0] -> band 18
            E[u * 36 + 6  + r] = xs[0]  * s0[r*36 + u*6]   + xs[1]  * s0[r*36 + u*6 + 1296];
            E[u * 36 + 18 + r] = xs[24] * s3[u*216 + r*36] + xs[25] * s3[u*216 + r*36 + 1296];
        }
    }
    __syncthreads();

    // ---- P2: chains j=1 ; build T32,T02 ----------------------------------
    chain36(6, 12, TA + 216, 6);    // row0
    chain36(18, 24, TA, 6);         // row3
    btile(TBs, SITE(3,2), xs[28], xs[29], 6, 6, 1, 216, 36);  // T32
    btile(EB,  SITE(0,2), xs[4],  xs[5],  6, 6, 1, 6,   36);  // T02 (EB as scratch)
    __syncthreads();

    // ---- P3: chains j=2 ---------------------------------------------------
    chain36(12, 6, EB, 36);         // row0
    chain36(24, 18, TBs, 36);       // row3
    __syncthreads();

    // ---- P4: chains j=3 -> E0 (cols 0-5) & EB ; build T10 -----------------
    for (int t2 = tid; t2 < 216 * 6; t2 += BLK) {
        int m = t2 / 6, n = t2 % 6;
        float a0 = 0.f, a3 = 0.f;
        #pragma unroll
        for (int k = 0; k < 6; ++k) {
            a0 = fmaf(E[m * 36 + 6  + k], TA[468 + k * 6 + n], a0);  // T03
            a3 = fmaf(E[m * 36 + 18 + k], TA[432 + k * 6 + n], a3);  // T33
        }
        E[((m % 36) * 6 + n) * 36 + m / 36] = a0;        // E0 [ (d1d2d3) ][ d0 ]
        EB[(m / 6) * 36 + (m % 6) * 6 + n]  = a3;        // EB [ (d0d1) ][ (d2d3) ]
    }
    btile(TBs, SITE(1,0), xs[8], xs[9], 6, 6, 216, 6, 36);   // T10 [u][d*6+r]
    __syncthreads();

    // ================= row 1 =================
    // P5: j=0 (K=6) + build T11 half1
    acc_zero(); big_K6(TBs);
    build_big_half(SITE(1,1), xs[10], xs[11], 0, 16);
    __syncthreads();
    write_rot();                                   // P6
    __syncthreads();
    // j=1 (K=36 split 16+20)
    acc_zero(); big_compute(TA, 0, 4);             // P7a
    __syncthreads();
    build_big_half(SITE(1,1), xs[10], xs[11], 16, 20);   // P7b
    __syncthreads();
    big_compute(TA, 16, 5);                        // P7c
    __syncthreads();
    write_rot();                                   // P8 + build T12 half1
    build_big_half(SITE(1,2), xs[12], xs[13], 0, 16);
    __syncthreads();
    // j=2
    acc_zero(); big_compute(TA, 0, 4);             // P9a
    __syncthreads();
    build_big_half(SITE(1,2), xs[12], xs[13], 16, 20);   // P9b
    __syncthreads();
    big_compute(TA, 16, 5);                        // P9c
    __syncthreads();
    write_rot();                                   // P10 + build T13 [u*6+l][d]
    for (int idx = tid; idx < 216; idx += BLK) {
        int k = idx / 6, n = idx % 6;
        int g = (k / 6) * 216 + (k % 6) + n * 6;
        const float* s = SITE(1,3);
        TBs[idx] = xs[14] * s[g] + xs[15] * s[g + 1296];
    }
    __syncthreads();
    // P11: j=3 tail (M=216,K=36,N=6) into registers
    float accT[6];
    {
        #pragma unroll
        for (int n = 0; n < 6; ++n) accT[n] = 0.f;
        if (tid < 216) {
            int m = tid;
            for (int kb = 0; kb < 9; ++kb) {
                float4 sv = *(const float4*)&E[m * 36 + kb * 4];
                const float* t0 = TBs + (kb * 4) * 6;
                #pragma unroll
                for (int n = 0; n < 6; ++n) accT[n] = fmaf(sv.x, t0[n],      accT[n]);
                #pragma unroll
                for (int n = 0; n < 6; ++n) accT[n] = fmaf(sv.y, t0[6 + n],  accT[n]);
                #pragma unroll
                for (int n = 0; n < 6; ++n) accT[n] = fmaf(sv.z, t0[12 + n], accT[n]);
                #pragma unroll
                for (int n = 0; n < 6; ++n) accT[n] = fmaf(sv.w, t0[18 + n], accT[n]);
            }
        }
    }
    __syncthreads();
    // P12: store env_top -> E0-layout (cols 0-5) + build T20
    if (tid < 216) {
        int m = tid;
        #pragma unroll
        for (int n = 0; n < 6; ++n)
            E[((m % 36) * 6 + n) * 36 + m / 36] = accT[n];
    }
    btile(TBs, SITE(2,0), xs[16], xs[17], 6, 6, 216, 6, 36);   // T20
    __syncthreads();

    // ================= row 2 =================
    acc_zero(); big_K6(TBs);                       // P13: j=0 + T21 half1
    build_big_half(SITE(2,1), xs[18], xs[19], 0, 16);
    __syncthreads();
    write_rot();                                   // P14 + build NT [(u*6+d)][l]
    for (int idx = tid; idx < 216; idx += BLK) {
        int k = idx / 6, n = idx % 6;
        int g = (k / 6) * 216 + (k % 6) * 6 + n;
        const float* s = SITE(2,3);
        TBs[idx] = xs[22] * s[g] + xs[23] * s[g + 1296];
    }
    __syncthreads();
    acc_zero(); big_compute(TA, 0, 4);             // P15a: j=1
    __syncthreads();
    build_big_half(SITE(2,1), xs[18], xs[19], 16, 20);   // P15b
    __syncthreads();
    big_compute(TA, 16, 5);                        // P15c
    __syncthreads();
    // P16: special store -> S_pre [ (u2,u3,r1) ][ (d0,d1) ]
    if (active) {
        #pragma unroll
        for (int i = 0; i < 8; ++i) {
            int m = mi + 27 * i;
            int rowb = (m / 6) * 6, colb = (m % 6) * 6;
            float v0 = acc[i].x, v1 = acc[i].y, v2 = acc[i].z, v3 = acc[i].w;
            int dr;
            dr = dr0 + 0; E[(rowb + dr % 6) * 36 + colb + dr / 6] = v0;
            dr = dr0 + 1; E[(rowb + dr % 6) * 36 + colb + dr / 6] = v1;
            dr = dr0 + 2; E[(rowb + dr % 6) * 36 + colb + dr / 6] = v2;
            dr = dr0 + 3; E[(rowb + dr % 6) * 36 + colb + dr / 6] = v3;
        }
    }
    __syncthreads();
    // P17: R = S_pre x EB  (tile = EB, full K=36)
    acc_zero(); big_compute(EB, 0, 9);
    __syncthreads();
    // P18: store R -> [ (u2,r1,d2) ][ (u3,d3) ]
    if (active) {
        #pragma unroll
        for (int i = 0; i < 8; ++i) {
            int m = mi + 27 * i;
            int rA = (m / 36) * 36 + (m % 6) * 6;      // u2*36 + r1*6
            int cB = ((m / 6) % 6) * 6;                // u3*6
            float v0 = acc[i].x, v1 = acc[i].y, v2 = acc[i].z, v3 = acc[i].w;
            int dr;
            dr = dr0 + 0; E[(rA + dr / 6) * 36 + cB + dr % 6] = v0;
            dr = dr0 + 1; E[(rA + dr / 6) * 36 + cB + dr % 6] = v1;
            dr = dr0 + 2; E[(rA + dr / 6) * 36 + cB + dr % 6] = v2;
            dr = dr0 + 3; E[(rA + dr / 6) * 36 + cB + dr % 6] = v3;
        }
    }
    __syncthreads();
    // P19: T1[m3][r2] = sum_k R[m3][k]*NT[k][r2] -> EB (EB dead after P17)
    if (tid < 216) {
        int m = tid;
        #pragma unroll
        for (int n = 0; n < 6; ++n) accT[n] = 0.f;
        for (int kb = 0; kb < 9; ++kb) {
            float4 sv = *(const float4*)&E[m * 36 + kb * 4];
            const float* t0 = TBs + (kb * 4) * 6;
            #pragma unroll
            for (int n = 0; n < 6; ++n) accT[n] = fmaf(sv.x, t0[n],      accT[n]);
            #pragma unroll
            for (int n = 0; n < 6; ++n) accT[n] = fmaf(sv.y, t0[6 + n],  accT[n]);
            #pragma unroll
            for (int n = 0; n < 6; ++n) accT[n] = fmaf(sv.z, t0[12 + n], accT[n]);
            #pragma unroll
            for (int n = 0; n < 6; ++n) accT[n] = fmaf(sv.w, t0[18 + n], accT[n]);
        }
        #pragma unroll
        for (int n = 0; n < 6; ++n) EB[m * 6 + n] = accT[n];
    }
    __syncthreads();

    // ---- P20: out[o] = sum_e T1[e] * (x20*C0 + x21*C1)[coff], normalize ----
    float part[10];
    #pragma unroll
    for (int o = 0; o < 10; ++o) part[o] = 0.f;
    {
        float x0 = xs[20], x1 = xs[21];
        for (int e = tid; e < 1296; e += BLK) {
            float t1 = EB[e];
            int m3 = e / 6;
            int u2 = m3 / 36, r1 = (m3 / 6) % 6, d2 = m3 % 6, r2 = e % 6;
            int coff = u2 * 216 + r2 * 36 + d2 * 6 + r1;
            #pragma unroll
            for (int o = 0; o < 10; ++o) {
                float c = x0 * pepsc[o * 1296 + coff]
                        + x1 * pepsc[(10 + o) * 1296 + coff];
                part[o] = fmaf(t1, c, part[o]);
            }
        }
    }
    #pragma unroll
    for (int off = 32; off >= 1; off >>= 1) {
        #pragma unroll
        for (int o = 0; o < 10; ++o)
            part[o] += __shfl_down(part[o], off, 64);
    }
    int lane = tid & 63, wid = tid >> 6;
    if (lane == 0) {
        #pragma unroll
        for (int o = 0; o < 10; ++o) red[wid * 10 + o] = part[o];
    }
    __syncthreads();
    if (tid < 10)
        red[40 + tid] = red[tid] + red[10 + tid] + red[20 + tid] + red[30 + tid];
    __syncthreads();
    if (tid == 0) {
        float n2 = 0.f;
        #pragma unroll
        for (int o = 0; o < 10; ++o) n2 += red[40 + o] * red[40 + o];
        red[50] = 1.0f / sqrtf(n2);
    }
    __syncthreads();
    if (tid < 10) out[b * 10 + tid] = red[40 + tid] * red[50];
    #undef SITE
}

extern "C" void kernel_launch(void* const* d_in, const int* in_sizes, int n_in,
                              void* d_out, int out_size, void* d_ws, size_t ws_size,
                              hipStream_t stream) {
    const float* inputs = (const float*)d_in[0];   // (B,4,4,2) f32
    const float* peps   = (const float*)d_in[1];   // (4,4,2,6,6,6,6) f32
    const float* pepsc  = (const float*)d_in[2];   // (2,10,6,6,6,6) f32
    float* outp = (float*)d_out;                   // (B,10) f32
    const int B = in_sizes[0] / 32;
    peps_fwd<<<dim3(B), dim3(BLK), 0, stream>>>(inputs, peps, pepsc, outp);
}

// Round 4
// 119.666 us; speedup vs baseline: 1.4829x; 1.0855x over previous
//
#include <hip/hip_runtime.h>
#include <math.h>

#define BLK 256

__device__ __forceinline__ void fma4(float4& a, float s, const float4& n) {
    a.x = fmaf(s, n.x, a.x); a.y = fmaf(s, n.y, a.y);
    a.z = fmaf(s, n.z, a.z); a.w = fmaf(s, n.w, a.w);
}

__global__ __launch_bounds__(BLK, 2)
void peps_fwd(const float* __restrict__ inputs,
              const float* __restrict__ peps,
              const float* __restrict__ pepsc,
              float* __restrict__ out)
{
    // 80736 B LDS -> 2 blocks/CU; grid 512 -> all blocks co-resident (1 round).
    // Two batches per block: every phase serves both, halving barriers/batch
    // and sharing all global weight loads between the two batches.
    __shared__ __align__(16) float E[2 * 7776];    // env per slot, [m<216][k<36]
    __shared__ __align__(16) float TA[2 * 720];    // big-tile half slot
    __shared__ __align__(16) float TBs[2 * 216];   // small tiles
    __shared__ __align__(16) float EB[2 * 1296];   // env_bot / T1
    __shared__ float xs[64];                        // x coeffs, 32 per slot
    __shared__ float red[104];                      // 52 per slot

    const int b0  = blockIdx.x * 2;
    const int tid = threadIdx.x;

    #define SITE(i, j) (peps + (size_t)((i) * 4 + (j)) * 2 * 1296)

    // big GEMM task split (M=216, N=36): 243 tasks, m = mi + 27*i interleaved
    const int di  = tid % 9;
    const int mi  = tid / 9;
    const int dr0 = di * 4;
    const bool active = (tid < 243);

    float4 acc[2][8];
    float accT[2][6];

    // x scaled by 100: constant positive per-node rescale, absorbed by the
    // final normalization; keeps the unnormalized chain well inside fp32 range.
    if (tid < 64) xs[tid] = inputs[b0 * 32 + tid] * 100.0f;

    // ---- helpers (dual-slot) ---------------------------------------------
    auto btile2 = [&](float* nd, int str, const float* site, int xi,
                      int Dd, int R, int sx, int sd, int sr) {
        int tot = 6 * Dd * R;
        for (int idx = tid; idx < tot; idx += BLK) {
            int x = idx / (Dd * R), rem = idx % (Dd * R);
            int d = rem / R, r = rem % R;
            int g = x * sx + d * sd + r * sr;
            float a = site[g], c = site[g + 1296];
            nd[idx]       = xs[xi]      * a + xs[xi + 1]  * c;
            nd[idx + str] = xs[32 + xi] * a + xs[33 + xi] * c;
        }
    };
    // big tile half: k-rows [k0,k0+kn) at local row 0, layout [k][d*6+r]
    auto build_big_half2 = [&](const float* site, int xi, int k0, int kn) {
        for (int idx = tid; idx < kn * 36; idx += BLK) {
            int k = k0 + idx / 36, n = idx % 36;
            int g = (k / 6) * 216 + (k % 6) + (n / 6) * 6 + (n % 6) * 36;
            float a = site[g], c = site[g + 1296];
            TA[idx]       = xs[xi]      * a + xs[xi + 1]  * c;
            TA[720 + idx] = xs[32 + xi] * a + xs[33 + xi] * c;
        }
    };
    auto acc_zero = [&]() {
        #pragma unroll
        for (int s = 0; s < 2; ++s)
            #pragma unroll
            for (int i = 0; i < 8; ++i)
                acc[s][i] = make_float4(0.f, 0.f, 0.f, 0.f);
    };
    auto big_compute = [&](int s, const float* TH, int k0, int kb_n) {
        if (!active) return;
        const float* Es = E + s * 7776;
        for (int kb = 0; kb < kb_n; ++kb) {
            float4 sv[8];
            #pragma unroll
            for (int i = 0; i < 8; ++i)
                sv[i] = *(const float4*)&Es[(mi + 27 * i) * 36 + k0 + kb * 4];
            const float* THb = TH + (kb * 4) * 36 + dr0;
            float4 n0 = *(const float4*)(THb);
            float4 n1 = *(const float4*)(THb + 36);
            float4 n2 = *(const float4*)(THb + 72);
            float4 n3 = *(const float4*)(THb + 108);
            #pragma unroll
            for (int i = 0; i < 8; ++i) {
                fma4(acc[s][i], sv[i].x, n0);
                fma4(acc[s][i], sv[i].y, n1);
                fma4(acc[s][i], sv[i].z, n2);
                fma4(acc[s][i], sv[i].w, n3);
            }
        }
    };
    auto big_K6 = [&](int s, const float* TH) {
        if (!active) return;
        const float* Es = E + s * 7776;
        float4 s4[8]; float2 s2[8];
        #pragma unroll
        for (int i = 0; i < 8; ++i) {
            const float* Ei = &Es[(mi + 27 * i) * 36];
            s4[i] = *(const float4*)(Ei);
            s2[i] = *(const float2*)(Ei + 4);
        }
        const float* THb = TH + dr0;
        float4 n0 = *(const float4*)(THb);
        float4 n1 = *(const float4*)(THb + 36);
        float4 n2 = *(const float4*)(THb + 72);
        float4 n3 = *(const float4*)(THb + 108);
        float4 n4 = *(const float4*)(THb + 144);
        float4 n5 = *(const float4*)(THb + 180);
        #pragma unroll
        for (int i = 0; i < 8; ++i) {
            fma4(acc[s][i], s4[i].x, n0);
            fma4(acc[s][i], s4[i].y, n1);
            fma4(acc[s][i], s4[i].z, n2);
            fma4(acc[s][i], s4[i].w, n3);
            fma4(acc[s][i], s2[i].x, n4);
            fma4(acc[s][i], s2[i].y, n5);
        }
    };
    // rotation store: out[m][(d,r)] -> row (m%36)*6+d, col (m/36)*6+r
    auto write_rot = [&](int s) {
        if (!active) return;
        float* Es = E + s * 7776;
        #pragma unroll
        for (int i = 0; i < 8; ++i) {
            int m = mi + 27 * i, mr = m % 36, mq = m / 36;
            float v0 = acc[s][i].x, v1 = acc[s][i].y, v2 = acc[s][i].z, v3 = acc[s][i].w;
            int dr;
            dr = dr0 + 0; Es[(mr * 6 + dr / 6) * 36 + mq * 6 + dr % 6] = v0;
            dr = dr0 + 1; Es[(mr * 6 + dr / 6) * 36 + mq * 6 + dr % 6] = v1;
            dr = dr0 + 2; Es[(mr * 6 + dr / 6) * 36 + mq * 6 + dr % 6] = v2;
            dr = dr0 + 3; Es[(mr * 6 + dr / 6) * 36 + mq * 6 + dr % 6] = v3;
        }
    };
    // boundary chain step (N=36, K=6, band cin -> band cout), dual slot
    auto chain36_2 = [&](int cin, int cout, const float* TL, int tstr, int M) {
        for (int t2 = tid; t2 < M * 36; t2 += BLK) {
            int m = t2 / 36, n = t2 % 36;
            float a0 = 0.f, a1 = 0.f;
            #pragma unroll
            for (int k = 0; k < 6; ++k) {
                a0 = fmaf(E[m * 36 + cin + k],        TL[k * 36 + n],        a0);
                a1 = fmaf(E[7776 + m * 36 + cin + k], TL[tstr + k * 36 + n], a1);
            }
            int oidx = (m * 6 + n / 6) * 36 + cout + n % 6;
            E[oidx] = a0;
            E[7776 + oidx] = a1;
        }
    };

    __syncthreads();  // P0: xs ready

    // ---- P1: boundary tiles + chain inits --------------------------------
    btile2(TA + 0,   720, SITE(3,1), 26, 6, 6, 1, 216, 36);  // T31 [x][u*6+r]
    btile2(TA + 216, 720, SITE(0,1), 2,  6, 6, 1, 6,   36);  // T01 [x][d*6+r]
    btile2(TA + 432, 720, SITE(3,3), 30, 6, 1, 1, 216, 0);   // T33 [x][u]
    btile2(TA + 468, 720, SITE(0,3), 6,  6, 1, 1, 6,   0);   // T03 [x][d]
    {
        const float* s3 = SITE(3,0);
        const float* s0 = SITE(0,0);
        for (int idx = tid; idx < 36; idx += BLK) {
            int u = idx / 6, r = idx % 6;
            float a0 = s0[r*36 + u*6],   c0 = s0[r*36 + u*6 + 1296];
            float a3 = s3[u*216 + r*36], c3 = s3[u*216 + r*36 + 1296];
            // row0 S0[d0][r0] -> band 6 ; row3 S0[u0][r0] -> band 18
            E[u * 36 + 6  + r]        = xs[0]  * a0 + xs[1]  * c0;
            E[7776 + u * 36 + 6  + r] = xs[32] * a0 + xs[33] * c0;
            E[u * 36 + 18 + r]        = xs[24] * a3 + xs[25] * c3;
            E[7776 + u * 36 + 18 + r] = xs[56] * a3 + xs[57] * c3;
        }
    }
    __syncthreads();

    // ---- P2: chains j=1 ; build T32,T02 ----------------------------------
    chain36_2(6, 12, TA + 216, 720, 6);    // row0
    chain36_2(18, 24, TA, 720, 6);         // row3
    btile2(TBs, 216, SITE(3,2), 28, 6, 6, 1, 216, 36);  // T32
    btile2(EB, 1296, SITE(0,2), 4,  6, 6, 1, 6,   36);  // T02 (EB as scratch)
    __syncthreads();

    // ---- P3: chains j=2 ---------------------------------------------------
    chain36_2(12, 6, EB, 1296, 36);        // row0
    chain36_2(24, 18, TBs, 216, 36);       // row3
    __syncthreads();

    // ---- P4: chains j=3 -> E0 (cols 0-5) & EB ; build T10 -----------------
    for (int t2 = tid; t2 < 216 * 6; t2 += BLK) {
        int m = t2 / 6, n = t2 % 6;
        float a00 = 0.f, a30 = 0.f, a01 = 0.f, a31 = 0.f;
        #pragma unroll
        for (int k = 0; k < 6; ++k) {
            a00 = fmaf(E[m*36 + 6  + k],        TA[468 + k*6 + n],       a00);  // T03
            a30 = fmaf(E[m*36 + 18 + k],        TA[432 + k*6 + n],       a30);  // T33
            a01 = fmaf(E[7776 + m*36 + 6  + k], TA[720 + 468 + k*6 + n], a01);
            a31 = fmaf(E[7776 + m*36 + 18 + k], TA[720 + 432 + k*6 + n], a31);
        }
        int e0i = ((m % 36) * 6 + n) * 36 + m / 36;       // E0 [ (d1d2d3) ][ d0 ]
        int ebi = (m / 6) * 36 + (m % 6) * 6 + n;         // EB [ (d0d1) ][ (d2d3) ]
        E[e0i] = a00;  E[7776 + e0i] = a01;
        EB[ebi] = a30; EB[1296 + ebi] = a31;
    }
    btile2(TBs, 216, SITE(1,0), 8, 6, 6, 216, 6, 36);     // T10 [u][d*6+r]
    __syncthreads();

    // ================= row 1 =================
    acc_zero();
    big_K6(0, TBs); big_K6(1, TBs + 216);                 // P5: j=0 + T11 half1
    build_big_half2(SITE(1,1), 10, 0, 16);
    __syncthreads();
    write_rot(0); write_rot(1);                           // P6
    __syncthreads();
    acc_zero();
    big_compute(0, TA, 0, 4); big_compute(1, TA + 720, 0, 4);    // P7a: j=1
    __syncthreads();
    build_big_half2(SITE(1,1), 10, 16, 20);               // P7b
    __syncthreads();
    big_compute(0, TA, 16, 5); big_compute(1, TA + 720, 16, 5);  // P7c
    __syncthreads();
    write_rot(0); write_rot(1);                           // P8 + T12 half1
    build_big_half2(SITE(1,2), 12, 0, 16);
    __syncthreads();
    acc_zero();
    big_compute(0, TA, 0, 4); big_compute(1, TA + 720, 0, 4);    // P9a: j=2
    __syncthreads();
    build_big_half2(SITE(1,2), 12, 16, 20);               // P9b
    __syncthreads();
    big_compute(0, TA, 16, 5); big_compute(1, TA + 720, 16, 5);  // P9c
    __syncthreads();
    write_rot(0); write_rot(1);                           // P10 + T13 [u*6+l][d]
    {
        const float* sP = SITE(1,3);
        for (int idx = tid; idx < 216; idx += BLK) {
            int k = idx / 6, n = idx % 6;
            int g = (k / 6) * 216 + (k % 6) + n * 6;
            float a = sP[g], c = sP[g + 1296];
            TBs[idx]       = xs[14] * a + xs[15] * c;
            TBs[216 + idx] = xs[46] * a + xs[47] * c;
        }
    }
    __syncthreads();
    // P11: j=3 tail (M=216,K=36,N=6) into registers
    #pragma unroll
    for (int s = 0; s < 2; ++s)
        #pragma unroll
        for (int n = 0; n < 6; ++n) accT[s][n] = 0.f;
    if (tid < 216) {
        int m = tid;
        #pragma unroll
        for (int s = 0; s < 2; ++s) {
            const float* Es = E + s * 7776;
            const float* Ts = TBs + s * 216;
            for (int kb = 0; kb < 9; ++kb) {
                float4 sv = *(const float4*)&Es[m * 36 + kb * 4];
                const float* t0 = Ts + (kb * 4) * 6;
                #pragma unroll
                for (int n = 0; n < 6; ++n) accT[s][n] = fmaf(sv.x, t0[n],      accT[s][n]);
                #pragma unroll
                for (int n = 0; n < 6; ++n) accT[s][n] = fmaf(sv.y, t0[6 + n],  accT[s][n]);
                #pragma unroll
                for (int n = 0; n < 6; ++n) accT[s][n] = fmaf(sv.z, t0[12 + n], accT[s][n]);
                #pragma unroll
                for (int n = 0; n < 6; ++n) accT[s][n] = fmaf(sv.w, t0[18 + n], accT[s][n]);
            }
        }
    }
    __syncthreads();
    // P12: store env_top (E0 layout, cols 0-5) + build T20
    if (tid < 216) {
        int m = tid;
        #pragma unroll
        for (int s = 0; s < 2; ++s)
            #pragma unroll
            for (int n = 0; n < 6; ++n)
                E[s * 7776 + ((m % 36) * 6 + n) * 36 + m / 36] = accT[s][n];
    }
    btile2(TBs, 216, SITE(2,0), 16, 6, 6, 216, 6, 36);    // T20
    __syncthreads();

    // ================= row 2 =================
    acc_zero();
    big_K6(0, TBs); big_K6(1, TBs + 216);                 // P13: j=0 + T21 half1
    build_big_half2(SITE(2,1), 18, 0, 16);
    __syncthreads();
    write_rot(0); write_rot(1);                           // P14 + NT [(u*6+d)][l]
    {
        const float* sP = SITE(2,3);
        for (int idx = tid; idx < 216; idx += BLK) {
            int k = idx / 6, n = idx % 6;
            int g = (k / 6) * 216 + (k % 6) * 6 + n;
            float a = sP[g], c = sP[g + 1296];
            TBs[idx]       = xs[22] * a + xs[23] * c;
            TBs[216 + idx] = xs[54] * a + xs[55] * c;
        }
    }
    __syncthreads();
    acc_zero();
    big_compute(0, TA, 0, 4); big_compute(1, TA + 720, 0, 4);    // P15a: j=1
    __syncthreads();
    build_big_half2(SITE(2,1), 18, 16, 20);               // P15b
    __syncthreads();
    big_compute(0, TA, 16, 5); big_compute(1, TA + 720, 16, 5);  // P15c
    __syncthreads();
    // P16: special store -> S_pre [ (u2,u3,r1) ][ (d0,d1) ]
    if (active) {
        #pragma unroll
        for (int s = 0; s < 2; ++s) {
            float* Es = E + s * 7776;
            #pragma unroll
            for (int i = 0; i < 8; ++i) {
                int m = mi + 27 * i;
                int rowb = (m / 6) * 6, colb = (m % 6) * 6;
                float v0 = acc[s][i].x, v1 = acc[s][i].y, v2 = acc[s][i].z, v3 = acc[s][i].w;
                int dr;
                dr = dr0 + 0; Es[(rowb + dr % 6) * 36 + colb + dr / 6] = v0;
                dr = dr0 + 1; Es[(rowb + dr % 6) * 36 + colb + dr / 6] = v1;
                dr = dr0 + 2; Es[(rowb + dr % 6) * 36 + colb + dr / 6] = v2;
                dr = dr0 + 3; Es[(rowb + dr % 6) * 36 + colb + dr / 6] = v3;
            }
        }
    }
    __syncthreads();
    // P17: R = S_pre x EB (full K=36)
    acc_zero();
    big_compute(0, EB, 0, 9); big_compute(1, EB + 1296, 0, 9);
    __syncthreads();
    // P18: store R -> [ (u2,r1,d2) ][ (u3,d3) ]
    if (active) {
        #pragma unroll
        for (int s = 0; s < 2; ++s) {
            float* Es = E + s * 7776;
            #pragma unroll
            for (int i = 0; i < 8; ++i) {
                int m = mi + 27 * i;
                int rA = (m / 36) * 36 + (m % 6) * 6;      // u2*36 + r1*6
                int cB = ((m / 6) % 6) * 6;                // u3*6
                float v0 = acc[s][i].x, v1 = acc[s][i].y, v2 = acc[s][i].z, v3 = acc[s][i].w;
                int dr;
                dr = dr0 + 0; Es[(rA + dr / 6) * 36 + cB + dr % 6] = v0;
                dr = dr0 + 1; Es[(rA + dr / 6) * 36 + cB + dr % 6] = v1;
                dr = dr0 + 2; Es[(rA + dr / 6) * 36 + cB + dr % 6] = v2;
                dr = dr0 + 3; Es[(rA + dr / 6) * 36 + cB + dr % 6] = v3;
            }
        }
    }
    __syncthreads();
    // P19: T1[m3][r2] = sum_k R[m3][k]*NT[k][r2] -> EB
    if (tid < 216) {
        int m = tid;
        #pragma unroll
        for (int s = 0; s < 2; ++s) {
            const float* Es = E + s * 7776;
            const float* Ts = TBs + s * 216;
            #pragma unroll
            for (int n = 0; n < 6; ++n) accT[s][n] = 0.f;
            for (int kb = 0; kb < 9; ++kb) {
                float4 sv = *(const float4*)&Es[m * 36 + kb * 4];
                const float* t0 = Ts + (kb * 4) * 6;
                #pragma unroll
                for (int n = 0; n < 6; ++n) accT[s][n] = fmaf(sv.x, t0[n],      accT[s][n]);
                #pragma unroll
                for (int n = 0; n < 6; ++n) accT[s][n] = fmaf(sv.y, t0[6 + n],  accT[s][n]);
                #pragma unroll
                for (int n = 0; n < 6; ++n) accT[s][n] = fmaf(sv.z, t0[12 + n], accT[s][n]);
                #pragma unroll
                for (int n = 0; n < 6; ++n) accT[s][n] = fmaf(sv.w, t0[18 + n], accT[s][n]);
            }
            #pragma unroll
            for (int n = 0; n < 6; ++n) EB[s * 1296 + m * 6 + n] = accT[s][n];
        }
    }
    __syncthreads();

    // ---- P20: out[o] = sum_e T1 * (x20*C0 + x21*C1), coalesced over coff ---
    float part[2][10];
    #pragma unroll
    for (int s = 0; s < 2; ++s)
        #pragma unroll
        for (int o = 0; o < 10; ++o) part[s][o] = 0.f;
    for (int c = tid; c < 1296; c += BLK) {
        int u2 = c / 216, r2 = (c / 36) % 6, d2 = (c / 6) % 6, r1 = c % 6;
        int e6 = u2 * 216 + r1 * 36 + d2 * 6 + r2;       // T1 index
        float t10 = EB[e6], t11 = EB[1296 + e6];
        #pragma unroll
        for (int o = 0; o < 10; ++o) {
            float c0 = pepsc[o * 1296 + c];
            float c1 = pepsc[(10 + o) * 1296 + c];
            float cc0 = xs[20] * c0 + xs[21] * c1;
            float cc1 = xs[52] * c0 + xs[53] * c1;
            part[0][o] = fmaf(t10, cc0, part[0][o]);
            part[1][o] = fmaf(t11, cc1, part[1][o]);
        }
    }
    #pragma unroll
    for (int off = 32; off >= 1; off >>= 1)
        #pragma unroll
        for (int s = 0; s < 2; ++s)
            #pragma unroll
            for (int o = 0; o < 10; ++o)
                part[s][o] += __shfl_down(part[s][o], off, 64);
    int lane = tid & 63, wid = tid >> 6;
    if (lane == 0) {
        #pragma unroll
        for (int s = 0; s < 2; ++s)
            #pragma unroll
            for (int o = 0; o < 10; ++o)
                red[s * 52 + wid * 10 + o] = part[s][o];
    }
    __syncthreads();
    {
        int s = tid >> 7, t = tid & 127;
        if (t < 10)
            red[s * 52 + 40 + t] = red[s * 52 + t] + red[s * 52 + 10 + t]
                                 + red[s * 52 + 20 + t] + red[s * 52 + 30 + t];
        __syncthreads();
        if (t == 0) {
            float n2 = 0.f;
            #pragma unroll
            for (int o = 0; o < 10; ++o) n2 += red[s * 52 + 40 + o] * red[s * 52 + 40 + o];
            red[s * 52 + 50] = 1.0f / sqrtf(n2);
        }
        __syncthreads();
        if (t < 10) out[(b0 + s) * 10 + t] = red[s * 52 + 40 + t] * red[s * 52 + 50];
    }
    #undef SITE
}

extern "C" void kernel_launch(void* const* d_in, const int* in_sizes, int n_in,
                              void* d_out, int out_size, void* d_ws, size_t ws_size,
                              hipStream_t stream) {
    const float* inputs = (const float*)d_in[0];   // (B,4,4,2) f32
    const float* peps   = (const float*)d_in[1];   // (4,4,2,6,6,6,6) f32
    const float* pepsc  = (const float*)d_in[2];   // (2,10,6,6,6,6) f32
    float* outp = (float*)d_out;                   // (B,10) f32
    const int B = in_sizes[0] / 32;
    peps_fwd<<<dim3(B / 2), dim3(BLK), 0, stream>>>(inputs, peps, pepsc, outp);
}